// Round 9
// baseline (144.707 us; speedup 1.0000x reference)
//
#include <hip/hip_runtime.h>
#include <math.h>

// InfoNCE (NT-Xent), N=8192, D=128, fp32 in, scalar fp32 out.
// Unified stacked Gram G=[g1n;g2n]*sqrt(5*log2e), fp8 e4m3, 2N x 128, stored
// FRAGMENT-MAJOR: byte k=8f+j of row r lives at P[((r>>5)*16+f)*256 + (r&31)*8 + j].
// Lower-triangle strip pairs only. MFMA = MX-scaled 32x32x64 f8f6f4, unit
// scales (0x7F e8m0), fmt fp8-e4m3.
//
// r15 (resubmit; round-8 bench was an env failure, kernel never ran):
// UNCAP THE REGISTER ALLOCATOR. r14's (512,4) produced VGPR_Count=64
// -> launch_bounds 2nd arg acts as min BLOCKS/CU (CUDA semantics): cap =
// 512/8 waves = 64 regs -> catastrophic spills (WRITE 103.7MB = 1.11M thr
// x ~95B spill footprint; spill reloads blew L2 -> FETCH 13->82MB; 77us).
// Retro-fit: r11-r13's "mystery writes" are per-thread-scaled spill stores
// too (66-84 B/thr) -> every version was spill-latency-bound (MfmaUtil
// ~10%). Fix: r13 structure (best: 57us) + launch_bounds(256,1) -> cap 512
// regs under either semantics; live set ~200-224 -> zero spills at 2
// waves/SIMD. ONE change vs r13 for clean attribution.
// Partials: part[81][2N]; slots 0..15 row partials (y), 16 mix (y==16),
// 17+4y+t col partials; diag tile's col slot stays zero -> uniform reduce.

constexpr int D = 128;
constexpr float E5 = 148.4131591025766f;   // e^5 (diag self-term)
constexpr int NSLOT = 81;

typedef __attribute__((ext_vector_type(16))) float f32x16;  // 32x32 MFMA acc
typedef __attribute__((ext_vector_type(8)))  int   v8i;     // 32-byte operand
typedef __attribute__((ext_vector_type(4)))  long  v4l;

// 32 rows per block, 8 threads per row (16 floats each). Per-row reduce via
// 3-step shuffle in the 8-lane group. P stores: 8B per frag chunk, two
// chunks per thread per matrix; each wave covers 8 full 64B lines per store.
__global__ __launch_bounds__(256) void normalize_kernel(
    const float4* __restrict__ h1, const float4* __restrict__ h2,
    unsigned char* __restrict__ P, float* __restrict__ d12,
    float* __restrict__ out, int N)
{
    const float SC = sqrtf(5.0f * 1.44269504088896340736f);  // sqrt(5*log2e)
    if (blockIdx.x == 0 && threadIdx.x == 0) out[0] = 0.f;

    const int tx   = threadIdx.x;
    const int rloc = tx >> 3;                 // 0..31  (row within block)
    const int t    = tx & 7;                  // 0..7   (16-float chunk)
    const int row  = blockIdx.x * 32 + rloc;

    float4 u[4], w[4];
#pragma unroll
    for (int i = 0; i < 4; ++i) {
        u[i] = h1[(size_t)row * 32 + t * 4 + i];
        w[i] = h2[(size_t)row * 32 + t * 4 + i];
    }
    float ss1 = 0.f, ss2 = 0.f, s12 = 0.f;
#pragma unroll
    for (int i = 0; i < 4; ++i) {
        ss1 += u[i].x*u[i].x + u[i].y*u[i].y + u[i].z*u[i].z + u[i].w*u[i].w;
        ss2 += w[i].x*w[i].x + w[i].y*w[i].y + w[i].z*w[i].z + w[i].w*w[i].w;
        s12 += u[i].x*w[i].x + u[i].y*w[i].y + u[i].z*w[i].z + u[i].w*w[i].w;
    }
#pragma unroll
    for (int off = 4; off > 0; off >>= 1) {   // reduce over the 8-lane group
        ss1 += __shfl_xor(ss1, off, 64);
        ss2 += __shfl_xor(ss2, off, 64);
        s12 += __shfl_xor(s12, off, 64);
    }
    float n1 = fmaxf(sqrtf(ss1), 1e-12f);
    float n2 = fmaxf(sqrtf(ss2), 1e-12f);
    float c1 = SC / n1, c2 = SC / n2;
    if (t == 0) d12[row] = 5.f * s12 / (n1 * n2);

    // pack 16 fp8 bytes per matrix: frags 2t (floats 0..7) and 2t+1 (8..15)
    int u0 = __builtin_amdgcn_cvt_pk_fp8_f32(u[0].x*c1, u[0].y*c1, 0, false);
    u0     = __builtin_amdgcn_cvt_pk_fp8_f32(u[0].z*c1, u[0].w*c1, u0, true);
    int u1 = __builtin_amdgcn_cvt_pk_fp8_f32(u[1].x*c1, u[1].y*c1, 0, false);
    u1     = __builtin_amdgcn_cvt_pk_fp8_f32(u[1].z*c1, u[1].w*c1, u1, true);
    int u2 = __builtin_amdgcn_cvt_pk_fp8_f32(u[2].x*c1, u[2].y*c1, 0, false);
    u2     = __builtin_amdgcn_cvt_pk_fp8_f32(u[2].z*c1, u[2].w*c1, u2, true);
    int u3 = __builtin_amdgcn_cvt_pk_fp8_f32(u[3].x*c1, u[3].y*c1, 0, false);
    u3     = __builtin_amdgcn_cvt_pk_fp8_f32(u[3].z*c1, u[3].w*c1, u3, true);
    int w0 = __builtin_amdgcn_cvt_pk_fp8_f32(w[0].x*c2, w[0].y*c2, 0, false);
    w0     = __builtin_amdgcn_cvt_pk_fp8_f32(w[0].z*c2, w[0].w*c2, w0, true);
    int w1 = __builtin_amdgcn_cvt_pk_fp8_f32(w[1].x*c2, w[1].y*c2, 0, false);
    w1     = __builtin_amdgcn_cvt_pk_fp8_f32(w[1].z*c2, w[1].w*c2, w1, true);
    int w2 = __builtin_amdgcn_cvt_pk_fp8_f32(w[2].x*c2, w[2].y*c2, 0, false);
    w2     = __builtin_amdgcn_cvt_pk_fp8_f32(w[2].z*c2, w[2].w*c2, w2, true);
    int w3 = __builtin_amdgcn_cvt_pk_fp8_f32(w[3].x*c2, w[3].y*c2, 0, false);
    w3     = __builtin_amdgcn_cvt_pk_fp8_f32(w[3].z*c2, w[3].w*c2, w3, true);

    unsigned long long ulo = (unsigned)u0 | ((unsigned long long)(unsigned)u1 << 32);
    unsigned long long uhi = (unsigned)u2 | ((unsigned long long)(unsigned)u3 << 32);
    unsigned long long wlo = (unsigned)w0 | ((unsigned long long)(unsigned)w1 << 32);
    unsigned long long whi = (unsigned)w2 | ((unsigned long long)(unsigned)w3 << 32);

    // dest: group g = row>>5 (= blockIdx.x for h1), frag f at g*4096 + f*256,
    // row slot (row&31)*8. h2 rows live at N+row -> group N/32 + blockIdx.x.
    size_t b1 = (size_t)blockIdx.x * 4096 + (size_t)t * 512 + (size_t)rloc * 8;
    size_t b2 = ((size_t)(N >> 5) + blockIdx.x) * 4096 + (size_t)t * 512 + (size_t)rloc * 8;
    *(unsigned long long*)(P + b1)       = ulo;
    *(unsigned long long*)(P + b1 + 256) = uhi;
    *(unsigned long long*)(P + b2)       = wlo;
    *(unsigned long long*)(P + b2 + 256) = whi;
}

// Load a 32-byte K=64 operand: lane holds k=(lhi*32..+31) of row l32 ->
// 4 frags at stride 256B, 8B each. Stays in 8 VGPRs (v4l -> v8i bitcast).
__device__ __forceinline__ v8i load_op(const unsigned char* p) {
    v4l t;
    t[0] = *(const long*)(p);
    t[1] = *(const long*)(p + 256);
    t[2] = *(const long*)(p + 512);
    t[3] = *(const long*)(p + 768);
    return __builtin_bit_cast(v8i, t);
}

// Strips of 128 rows over 2N=16384 -> 128 strips. Tiles (I,(I+d)&127):
// y<16 -> d=4y..4y+3 (nT=4); y==16, I<64 -> d=64 (nT=1). Each unordered
// strip pair exactly once. Block 256 thr (4 waves), wave tile 64x64.
// Strip base: P + strip*16384; col-half (+4096); frag f at +f*256; row l32*8.
// Operand for kchunk kc, lane half lhi: frags kc*8+lhi*4 .. +3.
__global__ __launch_bounds__(256, 1) void gram_mfma_kernel(
    const unsigned char* __restrict__ P, float* __restrict__ part, int N)
{
    const int I = blockIdx.x;
    int nT = 4, dBase = 0;
    if (blockIdx.y < 16) { dBase = blockIdx.y * 4; }
    else if (I < 64)     { nT = 1; dBase = 64; }
    else return;

    __shared__ float ldsRow[128];
    __shared__ float ldsCol[4][128];

    const int tx   = threadIdx.x;
    const int lane = tx & 63;
    const int l32  = lane & 31, lhi = lane >> 5;
    const int wi   = (tx >> 6) >> 1, wj = (tx >> 6) & 1;
    const int iBase = I * 128;
    const int fOff = lhi * 1024;   // lhi*4 frags * 256B

    // zero the block-local accumulators (one barrier before first ds_add)
    if (tx < 128) ldsRow[tx] = 0.f;
    {
        float* lc = &ldsCol[0][0];
        lc[tx] = 0.f;
        lc[tx + 256] = 0.f;
    }
    __syncthreads();

    // A-operands: a[st][kc], rows iBase+wi*64+st*32+l32, k = kc*64+lhi*32..+31
    v8i a[2][2];
#pragma unroll
    for (int st = 0; st < 2; ++st) {
        const unsigned char* xp =
            P + (size_t)(I * 4 + wi * 2 + st) * 4096 + fOff + l32 * 8;
#pragma unroll
        for (int kc = 0; kc < 2; ++kc)
            a[st][kc] = load_op(xp + kc * 2048);
    }

    float racc0[16], racc1[16];
#pragma unroll
    for (int r = 0; r < 16; ++r) { racc0[r] = 0.f; racc1[r] = 0.f; }

    const int j0 = wj * 64 + l32;
    const int j1 = j0 + 32;

#pragma unroll
    for (int t = 0; t < 4; ++t) {
        if (t >= nT) break;

        const int J = (I + dBase + t) & 127;
        const unsigned char* pb =
            P + (size_t)(J * 4 + wj * 2) * 4096 + fOff + l32 * 8;

        v8i b0[2], b1[2];
#pragma unroll
        for (int kc = 0; kc < 2; ++kc) {
            b0[kc] = load_op(pb + kc * 2048);
            b1[kc] = load_op(pb + 4096 + kc * 2048);
        }

        f32x16 acc00, acc01, acc10, acc11;
#pragma unroll
        for (int r = 0; r < 16; ++r) {
            acc00[r] = 0.f; acc01[r] = 0.f; acc10[r] = 0.f; acc11[r] = 0.f;
        }

#pragma unroll
        for (int kc = 0; kc < 2; ++kc) {
            acc00 = __builtin_amdgcn_mfma_scale_f32_32x32x64_f8f6f4(
                a[0][kc], b0[kc], acc00, 0, 0, 0, 127, 0, 127);
            acc10 = __builtin_amdgcn_mfma_scale_f32_32x32x64_f8f6f4(
                a[1][kc], b0[kc], acc10, 0, 0, 0, 127, 0, 127);
            acc01 = __builtin_amdgcn_mfma_scale_f32_32x32x64_f8f6f4(
                a[0][kc], b1[kc], acc01, 0, 0, 0, 127, 0, 127);
            acc11 = __builtin_amdgcn_mfma_scale_f32_32x32x64_f8f6f4(
                a[1][kc], b1[kc], acc11, 0, 0, 0, 127, 0, 127);
        }

        // epilogue: exp2 + row sums in regs; col sums straight to LDS
        float c0 = 0.f, c1 = 0.f;
#pragma unroll
        for (int r = 0; r < 16; ++r) {
            float e00 = __builtin_amdgcn_exp2f(acc00[r]);
            float e01 = __builtin_amdgcn_exp2f(acc01[r]);
            float e10 = __builtin_amdgcn_exp2f(acc10[r]);
            float e11 = __builtin_amdgcn_exp2f(acc11[r]);
            racc0[r] += e00 + e01;
            racc1[r] += e10 + e11;
            c0 += e00 + e10;
            c1 += e01 + e11;
        }
        if ((dBase + t) != 0) {            // diag tile: col sums = row sums
            c0 += __shfl_xor(c0, 32, 64);  // merge lhi halves
            c1 += __shfl_xor(c1, 32, 64);
            if (lane < 32) {               // on-CU ds atomics, no one waits
                atomicAdd(&ldsCol[t][j0], c0);
                atomicAdd(&ldsCol[t][j1], c1);
            }
        }
    }

    // flush row sums: butterfly over 32 col-lanes; C row=(r&3)+8*(r>>2)+4*lhi
#pragma unroll
    for (int r = 0; r < 16; ++r) {
        float s0 = racc0[r], s1 = racc1[r];
#pragma unroll
        for (int off = 1; off < 32; off <<= 1) {
            s0 += __shfl_xor(s0, off, 64);
            s1 += __shfl_xor(s1, off, 64);
        }
        if (l32 == 0) {
            int rowm = (r & 3) + 8 * (r >> 2) + 4 * lhi;
            atomicAdd(&ldsRow[wi * 64 + rowm], s0);
            atomicAdd(&ldsRow[wi * 64 + 32 + rowm], s1);
        }
    }

    __syncthreads();

    // writeout: plain coalesced stores of per-block partials.
    if (tx < 128) {
        const int y = blockIdx.y;
        part[(size_t)y * (2 * N) + iBase + tx] = ldsRow[tx];
#pragma unroll
        for (int t = 0; t < 4; ++t) {
            if (t >= nT) break;
            const int J = (I + dBase + t) & 127;
            const size_t slot = (y < 16) ? (size_t)(17 + y * 4 + t) : 16;
            part[slot * (2 * N) + (size_t)J * 128 + tx] = ldsCol[t][tx];
        }
    }
}

// rsum_i = sum over 81 partial slots; loss_i = 0.5*(log(rsum[i]-e5) +
// log(rsum[N+i]-e5)) - d12 ; out = mean
__global__ __launch_bounds__(256) void loss_reduce_kernel(
    const float* __restrict__ part, const float* __restrict__ d12,
    float* __restrict__ out, int N)
{
    __shared__ float sm[256];
    float s = 0.f;
    for (int i = blockIdx.x * 256 + threadIdx.x; i < N; i += gridDim.x * 256) {
        float r1 = 0.f, r2 = 0.f;
#pragma unroll 9
        for (int sl = 0; sl < NSLOT; ++sl) {
            r1 += part[(size_t)sl * (2 * N) + i];
            r2 += part[(size_t)sl * (2 * N) + N + i];
        }
        s += 0.5f * (logf(r1 - E5) + logf(r2 - E5)) - d12[i];
    }
    sm[threadIdx.x] = s;
    __syncthreads();
    for (int w = 128; w > 0; w >>= 1) {
        if (threadIdx.x < w) sm[threadIdx.x] += sm[threadIdx.x + w];
        __syncthreads();
    }
    if (threadIdx.x == 0) atomicAdd(out, sm[0] / (float)N);
}

extern "C" void kernel_launch(void* const* d_in, const int* in_sizes, int n_in,
                              void* d_out, int out_size, void* d_ws, size_t ws_size,
                              hipStream_t stream) {
    const float* h1 = (const float*)d_in[0];
    const float* h2 = (const float*)d_in[1];
    const int N = in_sizes[0] / D;   // 8192

    unsigned char* P = (unsigned char*)d_ws;                // 2N x 128 fp8, frag-major
    float* part = (float*)(P + (size_t)2 * N * D);          // 81 x 2N partials
    float* d12  = part + (size_t)NSLOT * 2 * N;             // N
    float* out  = (float*)d_out;

    normalize_kernel<<<N / 32, 256, 0, stream>>>(
        (const float4*)h1, (const float4*)h2, P, d12, out, N);

    dim3 grid(128, 17, 1);
    gram_mfma_kernel<<<grid, 256, 0, stream>>>(P, part, N);

    loss_reduce_kernel<<<64, 256, 0, stream>>>(part, d12, out, N);
}

// Round 10
// 136.846 us; speedup vs baseline: 1.0574x; 1.0574x over previous
//
#include <hip/hip_runtime.h>
#include <math.h>

// InfoNCE (NT-Xent), N=8192, D=128, fp32 in, scalar fp32 out.
// Unified stacked Gram G=[g1n;g2n]*sqrt(5*log2e), fp8 e4m3, 2N x 128, stored
// FRAGMENT-MAJOR: byte k=8f+j of row r lives at P[((r>>5)*16+f)*256 + (r&31)*8 + j].
// Lower-triangle strip pairs only. MFMA = MX-scaled 32x32x64 f8f6f4, unit
// scales (0x7F e8m0), fmt fp8-e4m3.
//
// r16: 32x64 WAVE TILES AT 4 WAVES/SIMD, SPILL-FREE. Ledger so far:
//  r13 (64x64 tiles, cap 128+64agpr): spills ~36MB -> 57us.
//  r14 (32x64 tiles, (512,4) -> 64-reg cap): catastrophic spills -> 77us.
//  r15 (64x64 tiles, uncapped): VGPR 152, WRITE collapsed to the logical
//      5.2MB (spill theory CONFIRMED) but occupancy ~1 wave/SIMD -> every
//      latency exposed, 82us. The 64x64 tile's ~216-reg live set can never
//      exceed 2 waves/SIMD: spill or starve.
// Fix: r14's 8-wave 32x64 structure (live ~110 regs) with launch_bounds
// (512,2): 16 waves/CU -> 128-reg cap >= 110 live -> no spills AND 4
// waves/SIMD of latency hiding. ONE token changed vs r14.
// Partials: part[81][2N]; slots 0..15 row partials (y), 16 mix (y==16),
// 17+4y+t col partials; diag tile's col slot stays zero -> uniform reduce.

constexpr int D = 128;
constexpr float E5 = 148.4131591025766f;   // e^5 (diag self-term)
constexpr int NSLOT = 81;

typedef __attribute__((ext_vector_type(16))) float f32x16;  // 32x32 MFMA acc
typedef __attribute__((ext_vector_type(8)))  int   v8i;     // 32-byte operand
typedef __attribute__((ext_vector_type(4)))  long  v4l;

// 32 rows per block, 8 threads per row (16 floats each). Per-row reduce via
// 3-step shuffle in the 8-lane group. P stores: 8B per frag chunk, two
// chunks per thread per matrix; each wave covers 8 full 64B lines per store.
__global__ __launch_bounds__(256) void normalize_kernel(
    const float4* __restrict__ h1, const float4* __restrict__ h2,
    unsigned char* __restrict__ P, float* __restrict__ d12,
    float* __restrict__ out, int N)
{
    const float SC = sqrtf(5.0f * 1.44269504088896340736f);  // sqrt(5*log2e)
    if (blockIdx.x == 0 && threadIdx.x == 0) out[0] = 0.f;

    const int tx   = threadIdx.x;
    const int rloc = tx >> 3;                 // 0..31  (row within block)
    const int t    = tx & 7;                  // 0..7   (16-float chunk)
    const int row  = blockIdx.x * 32 + rloc;

    float4 u[4], w[4];
#pragma unroll
    for (int i = 0; i < 4; ++i) {
        u[i] = h1[(size_t)row * 32 + t * 4 + i];
        w[i] = h2[(size_t)row * 32 + t * 4 + i];
    }
    float ss1 = 0.f, ss2 = 0.f, s12 = 0.f;
#pragma unroll
    for (int i = 0; i < 4; ++i) {
        ss1 += u[i].x*u[i].x + u[i].y*u[i].y + u[i].z*u[i].z + u[i].w*u[i].w;
        ss2 += w[i].x*w[i].x + w[i].y*w[i].y + w[i].z*w[i].z + w[i].w*w[i].w;
        s12 += u[i].x*w[i].x + u[i].y*w[i].y + u[i].z*w[i].z + u[i].w*w[i].w;
    }
#pragma unroll
    for (int off = 4; off > 0; off >>= 1) {   // reduce over the 8-lane group
        ss1 += __shfl_xor(ss1, off, 64);
        ss2 += __shfl_xor(ss2, off, 64);
        s12 += __shfl_xor(s12, off, 64);
    }
    float n1 = fmaxf(sqrtf(ss1), 1e-12f);
    float n2 = fmaxf(sqrtf(ss2), 1e-12f);
    float c1 = SC / n1, c2 = SC / n2;
    if (t == 0) d12[row] = 5.f * s12 / (n1 * n2);

    // pack 16 fp8 bytes per matrix: frags 2t (floats 0..7) and 2t+1 (8..15)
    int u0 = __builtin_amdgcn_cvt_pk_fp8_f32(u[0].x*c1, u[0].y*c1, 0, false);
    u0     = __builtin_amdgcn_cvt_pk_fp8_f32(u[0].z*c1, u[0].w*c1, u0, true);
    int u1 = __builtin_amdgcn_cvt_pk_fp8_f32(u[1].x*c1, u[1].y*c1, 0, false);
    u1     = __builtin_amdgcn_cvt_pk_fp8_f32(u[1].z*c1, u[1].w*c1, u1, true);
    int u2 = __builtin_amdgcn_cvt_pk_fp8_f32(u[2].x*c1, u[2].y*c1, 0, false);
    u2     = __builtin_amdgcn_cvt_pk_fp8_f32(u[2].z*c1, u[2].w*c1, u2, true);
    int u3 = __builtin_amdgcn_cvt_pk_fp8_f32(u[3].x*c1, u[3].y*c1, 0, false);
    u3     = __builtin_amdgcn_cvt_pk_fp8_f32(u[3].z*c1, u[3].w*c1, u3, true);
    int w0 = __builtin_amdgcn_cvt_pk_fp8_f32(w[0].x*c2, w[0].y*c2, 0, false);
    w0     = __builtin_amdgcn_cvt_pk_fp8_f32(w[0].z*c2, w[0].w*c2, w0, true);
    int w1 = __builtin_amdgcn_cvt_pk_fp8_f32(w[1].x*c2, w[1].y*c2, 0, false);
    w1     = __builtin_amdgcn_cvt_pk_fp8_f32(w[1].z*c2, w[1].w*c2, w1, true);
    int w2 = __builtin_amdgcn_cvt_pk_fp8_f32(w[2].x*c2, w[2].y*c2, 0, false);
    w2     = __builtin_amdgcn_cvt_pk_fp8_f32(w[2].z*c2, w[2].w*c2, w2, true);
    int w3 = __builtin_amdgcn_cvt_pk_fp8_f32(w[3].x*c2, w[3].y*c2, 0, false);
    w3     = __builtin_amdgcn_cvt_pk_fp8_f32(w[3].z*c2, w[3].w*c2, w3, true);

    unsigned long long ulo = (unsigned)u0 | ((unsigned long long)(unsigned)u1 << 32);
    unsigned long long uhi = (unsigned)u2 | ((unsigned long long)(unsigned)u3 << 32);
    unsigned long long wlo = (unsigned)w0 | ((unsigned long long)(unsigned)w1 << 32);
    unsigned long long whi = (unsigned)w2 | ((unsigned long long)(unsigned)w3 << 32);

    // dest: group g = row>>5 (= blockIdx.x for h1), frag f at g*4096 + f*256,
    // row slot (row&31)*8. h2 rows live at N+row -> group N/32 + blockIdx.x.
    size_t b1 = (size_t)blockIdx.x * 4096 + (size_t)t * 512 + (size_t)rloc * 8;
    size_t b2 = ((size_t)(N >> 5) + blockIdx.x) * 4096 + (size_t)t * 512 + (size_t)rloc * 8;
    *(unsigned long long*)(P + b1)       = ulo;
    *(unsigned long long*)(P + b1 + 256) = uhi;
    *(unsigned long long*)(P + b2)       = wlo;
    *(unsigned long long*)(P + b2 + 256) = whi;
}

// Load a 32-byte K=64 operand: lane holds k=(lhi*32..+31) of row l32 ->
// 4 frags at stride 256B, 8B each. Stays in 8 VGPRs (v4l -> v8i bitcast).
__device__ __forceinline__ v8i load_op(const unsigned char* p) {
    v4l t;
    t[0] = *(const long*)(p);
    t[1] = *(const long*)(p + 256);
    t[2] = *(const long*)(p + 512);
    t[3] = *(const long*)(p + 768);
    return __builtin_bit_cast(v8i, t);
}

// Strips of 128 rows over 2N=16384 -> 128 strips. Tiles (I,(I+d)&127):
// y<16 -> d=4y..4y+3 (nT=4); y==16, I<64 -> d=64 (nT=1). Block = 512 thr
// (8 waves): wr = wave>>1 picks the 32-row quarter, wc = wave&1 the 64-col
// half -> wave tile 32x64, acc = 2 x f32x16. Strip sub-block s (32 rows):
// P + (strip*4+s)*4096; frag f at +f*256; lane row at l32*8; kchunk kc,
// lane-half lhi -> frags kc*8+lhi*4 .. +3 (fOff = lhi*1024, +kc*2048).
__global__ __launch_bounds__(512, 2) void gram_mfma_kernel(
    const unsigned char* __restrict__ P, float* __restrict__ part, int N)
{
    const int I = blockIdx.x;
    int nT = 4, dBase = 0;
    if (blockIdx.y < 16) { dBase = blockIdx.y * 4; }
    else if (I < 64)     { nT = 1; dBase = 64; }
    else return;

    __shared__ float ldsRow[128];
    __shared__ float ldsCol[4][128];

    const int tx   = threadIdx.x;
    const int lane = tx & 63;
    const int l32  = lane & 31, lhi = lane >> 5;
    const int wid  = tx >> 6;
    const int wr   = wid >> 1;          // 0..3: 32-row quarter
    const int wc   = wid & 1;           // 0..1: 64-col half
    const int iBase = I * 128;
    const int fOff = lhi * 1024;        // lhi*4 frags * 256B

    // zero block-local accumulators (512 thr: ldsRow 128 + ldsCol 512)
    if (tx < 128) ldsRow[tx] = 0.f;
    ((float*)ldsCol)[tx] = 0.f;
    __syncthreads();

    // A-operand: rows iBase + wr*32 + l32, k = kc*64 + lhi*32 .. +31
    v8i a[2];
    {
        const unsigned char* xp =
            P + (size_t)(I * 4 + wr) * 4096 + fOff + l32 * 8;
        a[0] = load_op(xp);
        a[1] = load_op(xp + 2048);
    }

    float racc[16];
#pragma unroll
    for (int r = 0; r < 16; ++r) racc[r] = 0.f;

    const int j0 = wc * 64 + l32;

#pragma unroll
    for (int t = 0; t < 4; ++t) {
        if (t >= nT) break;

        const int J = (I + dBase + t) & 127;
        const unsigned char* pb =
            P + (size_t)(J * 4 + wc * 2) * 4096 + fOff + l32 * 8;

        v8i b0[2], b1[2];
#pragma unroll
        for (int kc = 0; kc < 2; ++kc) {
            b0[kc] = load_op(pb + kc * 2048);
            b1[kc] = load_op(pb + 4096 + kc * 2048);
        }

        f32x16 acc0, acc1;
#pragma unroll
        for (int r = 0; r < 16; ++r) { acc0[r] = 0.f; acc1[r] = 0.f; }

#pragma unroll
        for (int kc = 0; kc < 2; ++kc) {
            acc0 = __builtin_amdgcn_mfma_scale_f32_32x32x64_f8f6f4(
                a[kc], b0[kc], acc0, 0, 0, 0, 127, 0, 127);
            acc1 = __builtin_amdgcn_mfma_scale_f32_32x32x64_f8f6f4(
                a[kc], b1[kc], acc1, 0, 0, 0, 127, 0, 127);
        }

        // epilogue: exp2; row sums into racc (regs), col sums into LDS
        float c0 = 0.f, c1 = 0.f;
#pragma unroll
        for (int r = 0; r < 16; ++r) {
            float e0 = __builtin_amdgcn_exp2f(acc0[r]);
            float e1 = __builtin_amdgcn_exp2f(acc1[r]);
            racc[r] += e0 + e1;
            c0 += e0;
            c1 += e1;
        }
        if ((dBase + t) != 0) {            // diag tile: col sums == row sums
            c0 += __shfl_xor(c0, 32, 64);  // merge lhi halves
            c1 += __shfl_xor(c1, 32, 64);
            if (lane < 32) {               // on-CU ds atomics
                atomicAdd(&ldsCol[t][j0], c0);
                atomicAdd(&ldsCol[t][j0 + 32], c1);
            }
        }
    }

    // flush row sums: butterfly over 32 col-lanes; C row=(r&3)+8*(r>>2)+4*lhi
#pragma unroll
    for (int r = 0; r < 16; ++r) {
        float s = racc[r];
#pragma unroll
        for (int off = 1; off < 32; off <<= 1)
            s += __shfl_xor(s, off, 64);
        if (l32 == 0) {
            int rowm = (r & 3) + 8 * (r >> 2) + 4 * lhi;
            atomicAdd(&ldsRow[wr * 32 + rowm], s);
        }
    }

    __syncthreads();

    // writeout: plain coalesced stores of per-block partials.
    if (tx < 128) {
        const int y = blockIdx.y;
        part[(size_t)y * (2 * N) + iBase + tx] = ldsRow[tx];
#pragma unroll
        for (int t = 0; t < 4; ++t) {
            if (t >= nT) break;
            const int J = (I + dBase + t) & 127;
            const size_t slot = (y < 16) ? (size_t)(17 + y * 4 + t) : 16;
            part[slot * (2 * N) + (size_t)J * 128 + tx] = ldsCol[t][tx];
        }
    }
}

// rsum_i = sum over 81 partial slots; loss_i = 0.5*(log(rsum[i]-e5) +
// log(rsum[N+i]-e5)) - d12 ; out = mean
__global__ __launch_bounds__(256) void loss_reduce_kernel(
    const float* __restrict__ part, const float* __restrict__ d12,
    float* __restrict__ out, int N)
{
    __shared__ float sm[256];
    float s = 0.f;
    for (int i = blockIdx.x * 256 + threadIdx.x; i < N; i += gridDim.x * 256) {
        float r1 = 0.f, r2 = 0.f;
#pragma unroll 9
        for (int sl = 0; sl < NSLOT; ++sl) {
            r1 += part[(size_t)sl * (2 * N) + i];
            r2 += part[(size_t)sl * (2 * N) + N + i];
        }
        s += 0.5f * (logf(r1 - E5) + logf(r2 - E5)) - d12[i];
    }
    sm[threadIdx.x] = s;
    __syncthreads();
    for (int w = 128; w > 0; w >>= 1) {
        if (threadIdx.x < w) sm[threadIdx.x] += sm[threadIdx.x + w];
        __syncthreads();
    }
    if (threadIdx.x == 0) atomicAdd(out, sm[0] / (float)N);
}

extern "C" void kernel_launch(void* const* d_in, const int* in_sizes, int n_in,
                              void* d_out, int out_size, void* d_ws, size_t ws_size,
                              hipStream_t stream) {
    const float* h1 = (const float*)d_in[0];
    const float* h2 = (const float*)d_in[1];
    const int N = in_sizes[0] / D;   // 8192

    unsigned char* P = (unsigned char*)d_ws;                // 2N x 128 fp8, frag-major
    float* part = (float*)(P + (size_t)2 * N * D);          // 81 x 2N partials
    float* d12  = part + (size_t)NSLOT * 2 * N;             // N
    float* out  = (float*)d_out;

    normalize_kernel<<<N / 32, 256, 0, stream>>>(
        (const float4*)h1, (const float4*)h2, P, d12, out, N);

    dim3 grid(128, 17, 1);
    gram_mfma_kernel<<<grid, 512, 0, stream>>>(P, part, N);

    loss_reduce_kernel<<<64, 256, 0, stream>>>(part, d12, out, N);
}

// Round 11
// 131.943 us; speedup vs baseline: 1.0967x; 1.0372x over previous
//
#include <hip/hip_runtime.h>
#include <math.h>

// InfoNCE (NT-Xent), N=8192, D=128, fp32 in, scalar fp32 out.
// Unified stacked Gram G=[g1n;g2n]*sqrt(5*log2e), fp8 e4m3, 2N x 128, stored
// FRAGMENT-MAJOR: byte k=8f+j of row r at P[((r>>5)*16+f)*256 + (r&31)*8 + j].
// Lower-triangle strip pairs. MFMA = MX-scaled 32x32x64 f8f6f4, unit scales.
//
// r17: INDEPENDENT SMALL BLOCKS FOR LATENCY HIDING. Ledger: r15/r16 proved
// spills gone (WRITE == logical) but gram stuck at 75-82us with MfmaUtil
// ~9%, occupancy ~20%: the 512-thr 8-wave block is the granularity -- a
// second block needs 4 waves/SIMD so only ONE lockstep block/CU is ever
// resident; every tile's L2-load->MFMA->exp2 chain is exposed. Fix: 4-wave
// 256-thr blocks (64 rows x 128 cols, wave tile 32x64 unchanged, ~130 regs
// incl AGPR) + launch_bounds(256,3) -> 3-4 INDEPENDENT blocks/CU (m114:
// implicit wave-overlap needs ~3 blocks/CU). Grid (128,17,2): z = row half.
// y==16 now rows-only d=64 for ALL I (pair computed from both sides, +0.8%
// compute) -- kills the mix-slot special case cleanly.
// Partials part[145][2N]: slots 0..16 = row partials (y; z-halves disjoint);
// 17+(4y+t)*2+z = col partials (y<16); diag (y=0,t=0) writes zeros ->
// uniform 145-slot reduce.

constexpr int D = 128;
constexpr float E5 = 148.4131591025766f;   // e^5 (diag self-term)
constexpr int NSLOT = 145;

typedef __attribute__((ext_vector_type(16))) float f32x16;  // 32x32 MFMA acc
typedef __attribute__((ext_vector_type(8)))  int   v8i;     // 32-byte operand
typedef __attribute__((ext_vector_type(4)))  long  v4l;

// 32 rows per block, 8 threads per row (16 floats each). Per-row reduce via
// 3-step shuffle in the 8-lane group. P stores: 8B per frag chunk, two
// chunks per thread per matrix; each wave covers 8 full 64B lines per store.
__global__ __launch_bounds__(256) void normalize_kernel(
    const float4* __restrict__ h1, const float4* __restrict__ h2,
    unsigned char* __restrict__ P, float* __restrict__ d12,
    float* __restrict__ out, int N)
{
    const float SC = sqrtf(5.0f * 1.44269504088896340736f);  // sqrt(5*log2e)
    if (blockIdx.x == 0 && threadIdx.x == 0) out[0] = 0.f;

    const int tx   = threadIdx.x;
    const int rloc = tx >> 3;                 // 0..31  (row within block)
    const int t    = tx & 7;                  // 0..7   (16-float chunk)
    const int row  = blockIdx.x * 32 + rloc;

    float4 u[4], w[4];
#pragma unroll
    for (int i = 0; i < 4; ++i) {
        u[i] = h1[(size_t)row * 32 + t * 4 + i];
        w[i] = h2[(size_t)row * 32 + t * 4 + i];
    }
    float ss1 = 0.f, ss2 = 0.f, s12 = 0.f;
#pragma unroll
    for (int i = 0; i < 4; ++i) {
        ss1 += u[i].x*u[i].x + u[i].y*u[i].y + u[i].z*u[i].z + u[i].w*u[i].w;
        ss2 += w[i].x*w[i].x + w[i].y*w[i].y + w[i].z*w[i].z + w[i].w*w[i].w;
        s12 += u[i].x*w[i].x + u[i].y*w[i].y + u[i].z*w[i].z + u[i].w*w[i].w;
    }
#pragma unroll
    for (int off = 4; off > 0; off >>= 1) {   // reduce over the 8-lane group
        ss1 += __shfl_xor(ss1, off, 64);
        ss2 += __shfl_xor(ss2, off, 64);
        s12 += __shfl_xor(s12, off, 64);
    }
    float n1 = fmaxf(sqrtf(ss1), 1e-12f);
    float n2 = fmaxf(sqrtf(ss2), 1e-12f);
    float c1 = SC / n1, c2 = SC / n2;
    if (t == 0) d12[row] = 5.f * s12 / (n1 * n2);

    // pack 16 fp8 bytes per matrix: frags 2t (floats 0..7) and 2t+1 (8..15)
    int u0 = __builtin_amdgcn_cvt_pk_fp8_f32(u[0].x*c1, u[0].y*c1, 0, false);
    u0     = __builtin_amdgcn_cvt_pk_fp8_f32(u[0].z*c1, u[0].w*c1, u0, true);
    int u1 = __builtin_amdgcn_cvt_pk_fp8_f32(u[1].x*c1, u[1].y*c1, 0, false);
    u1     = __builtin_amdgcn_cvt_pk_fp8_f32(u[1].z*c1, u[1].w*c1, u1, true);
    int u2 = __builtin_amdgcn_cvt_pk_fp8_f32(u[2].x*c1, u[2].y*c1, 0, false);
    u2     = __builtin_amdgcn_cvt_pk_fp8_f32(u[2].z*c1, u[2].w*c1, u2, true);
    int u3 = __builtin_amdgcn_cvt_pk_fp8_f32(u[3].x*c1, u[3].y*c1, 0, false);
    u3     = __builtin_amdgcn_cvt_pk_fp8_f32(u[3].z*c1, u[3].w*c1, u3, true);
    int w0 = __builtin_amdgcn_cvt_pk_fp8_f32(w[0].x*c2, w[0].y*c2, 0, false);
    w0     = __builtin_amdgcn_cvt_pk_fp8_f32(w[0].z*c2, w[0].w*c2, w0, true);
    int w1 = __builtin_amdgcn_cvt_pk_fp8_f32(w[1].x*c2, w[1].y*c2, 0, false);
    w1     = __builtin_amdgcn_cvt_pk_fp8_f32(w[1].z*c2, w[1].w*c2, w1, true);
    int w2 = __builtin_amdgcn_cvt_pk_fp8_f32(w[2].x*c2, w[2].y*c2, 0, false);
    w2     = __builtin_amdgcn_cvt_pk_fp8_f32(w[2].z*c2, w[2].w*c2, w2, true);
    int w3 = __builtin_amdgcn_cvt_pk_fp8_f32(w[3].x*c2, w[3].y*c2, 0, false);
    w3     = __builtin_amdgcn_cvt_pk_fp8_f32(w[3].z*c2, w[3].w*c2, w3, true);

    unsigned long long ulo = (unsigned)u0 | ((unsigned long long)(unsigned)u1 << 32);
    unsigned long long uhi = (unsigned)u2 | ((unsigned long long)(unsigned)u3 << 32);
    unsigned long long wlo = (unsigned)w0 | ((unsigned long long)(unsigned)w1 << 32);
    unsigned long long whi = (unsigned)w2 | ((unsigned long long)(unsigned)w3 << 32);

    // dest: group g = row>>5 (= blockIdx.x for h1), frag f at g*4096 + f*256,
    // row slot (row&31)*8. h2 rows live at N+row -> group N/32 + blockIdx.x.
    size_t b1 = (size_t)blockIdx.x * 4096 + (size_t)t * 512 + (size_t)rloc * 8;
    size_t b2 = ((size_t)(N >> 5) + blockIdx.x) * 4096 + (size_t)t * 512 + (size_t)rloc * 8;
    *(unsigned long long*)(P + b1)       = ulo;
    *(unsigned long long*)(P + b1 + 256) = uhi;
    *(unsigned long long*)(P + b2)       = wlo;
    *(unsigned long long*)(P + b2 + 256) = whi;
}

// Load a 32-byte K=64 operand: lane holds k=(lhi*32..+31) of row l32 ->
// 4 frags at stride 256B, 8B each. Stays in 8 VGPRs (v4l -> v8i bitcast).
__device__ __forceinline__ v8i load_op(const unsigned char* p) {
    v4l t;
    t[0] = *(const long*)(p);
    t[1] = *(const long*)(p + 256);
    t[2] = *(const long*)(p + 512);
    t[3] = *(const long*)(p + 768);
    return __builtin_bit_cast(v8i, t);
}

// Strips of 128 rows over 2N=16384 -> 128 strips. Block (I, y, z):
// rows = I*128 + z*64 .. +63; y<16: tiles J=(I+4y+t)&127, t=0..3, rows+cols;
// y==16: J=(I+64)&127, rows ONLY (pair computed from both sides).
// Block = 256 thr, 4 waves: wr=row 32-half, wc=col 64-half; wave tile 32x64.
// Sub-block s of strip (32 rows): P + s*4096; frag f at +f*256; row l32*8;
// kchunk kc, lane-half lhi -> fOff = lhi*1024, +kc*2048.
__global__ __launch_bounds__(256, 3) void gram_mfma_kernel(
    const unsigned char* __restrict__ P, float* __restrict__ part, int N)
{
    const int I = blockIdx.x;
    const int z = blockIdx.z;
    int nT = 4, dBase = 0;
    bool doCols = true;
    if (blockIdx.y < 16) { dBase = blockIdx.y * 4; }
    else                 { nT = 1; dBase = 64; doCols = false; }

    __shared__ float ldsRow[64];
    __shared__ float ldsCol[4][128];

    const int tx   = threadIdx.x;
    const int lane = tx & 63;
    const int l32  = lane & 31, lhi = lane >> 5;
    const int wid  = tx >> 6;
    const int wr   = wid >> 1;          // 0..1: 32-row half of the 64 rows
    const int wc   = wid & 1;           // 0..1: 64-col half
    const int iBase = I * 128 + z * 64;
    const int fOff = lhi * 1024;        // lhi*4 frags * 256B

    // zero block-local accumulators (64 + 512 floats, 256 thr)
    if (tx < 64) ldsRow[tx] = 0.f;
    ((float*)ldsCol)[tx] = 0.f;
    ((float*)ldsCol)[tx + 256] = 0.f;
    __syncthreads();

    // A-operand: rows iBase + wr*32 + l32 -> sub-block I*4 + z*2 + wr
    v8i a[2];
    {
        const unsigned char* xp =
            P + (size_t)(I * 4 + z * 2 + wr) * 4096 + fOff + l32 * 8;
        a[0] = load_op(xp);
        a[1] = load_op(xp + 2048);
    }

    float racc[16];
#pragma unroll
    for (int r = 0; r < 16; ++r) racc[r] = 0.f;

    const int j0 = wc * 64 + l32;

#pragma unroll
    for (int t = 0; t < 4; ++t) {
        if (t >= nT) break;

        const int J = (I + dBase + t) & 127;
        const unsigned char* pb =
            P + (size_t)(J * 4 + wc * 2) * 4096 + fOff + l32 * 8;

        v8i b0[2], b1[2];
#pragma unroll
        for (int kc = 0; kc < 2; ++kc) {
            b0[kc] = load_op(pb + kc * 2048);
            b1[kc] = load_op(pb + 4096 + kc * 2048);
        }

        f32x16 acc0, acc1;
#pragma unroll
        for (int r = 0; r < 16; ++r) { acc0[r] = 0.f; acc1[r] = 0.f; }

#pragma unroll
        for (int kc = 0; kc < 2; ++kc) {
            acc0 = __builtin_amdgcn_mfma_scale_f32_32x32x64_f8f6f4(
                a[kc], b0[kc], acc0, 0, 0, 0, 127, 0, 127);
            acc1 = __builtin_amdgcn_mfma_scale_f32_32x32x64_f8f6f4(
                a[kc], b1[kc], acc1, 0, 0, 0, 127, 0, 127);
        }

        // epilogue: exp2; row sums into racc (regs), col sums into LDS
        float c0 = 0.f, c1 = 0.f;
#pragma unroll
        for (int r = 0; r < 16; ++r) {
            float e0 = __builtin_amdgcn_exp2f(acc0[r]);
            float e1 = __builtin_amdgcn_exp2f(acc1[r]);
            racc[r] += e0 + e1;
            c0 += e0;
            c1 += e1;
        }
        if (doCols && (dBase + t) != 0) {  // diag tile: col sums == row sums
            c0 += __shfl_xor(c0, 32, 64);  // merge lhi halves
            c1 += __shfl_xor(c1, 32, 64);
            if (lane < 32) {               // on-CU ds atomics
                atomicAdd(&ldsCol[t][j0], c0);
                atomicAdd(&ldsCol[t][j0 + 32], c1);
            }
        }
    }

    // flush row sums: butterfly over 32 col-lanes; C row=(r&3)+8*(r>>2)+4*lhi
#pragma unroll
    for (int r = 0; r < 16; ++r) {
        float s = racc[r];
#pragma unroll
        for (int off = 1; off < 32; off <<= 1)
            s += __shfl_xor(s, off, 64);
        if (l32 == 0) {
            int rowm = (r & 3) + 8 * (r >> 2) + 4 * lhi;
            atomicAdd(&ldsRow[wr * 32 + rowm], s);
        }
    }

    __syncthreads();

    // writeout: plain coalesced stores of per-block partials.
    {
        const int y = blockIdx.y;
        if (tx < 64)
            part[(size_t)y * (2 * N) + iBase + tx] = ldsRow[tx];
        if (doCols && tx < 128) {
#pragma unroll
            for (int t = 0; t < 4; ++t) {
                const int J = (I + dBase + t) & 127;
                const size_t slot = (size_t)(17 + (y * 4 + t) * 2 + z);
                part[slot * (2 * N) + (size_t)J * 128 + tx] = ldsCol[t][tx];
            }
        }
    }
}

// rsum_i = sum over 145 partial slots; loss_i = 0.5*(log(rsum[i]-e5) +
// log(rsum[N+i]-e5)) - d12 ; out = mean
__global__ __launch_bounds__(256) void loss_reduce_kernel(
    const float* __restrict__ part, const float* __restrict__ d12,
    float* __restrict__ out, int N)
{
    __shared__ float sm[256];
    float s = 0.f;
    for (int i = blockIdx.x * 256 + threadIdx.x; i < N; i += gridDim.x * 256) {
        float r1 = 0.f, r2 = 0.f;
#pragma unroll 5
        for (int sl = 0; sl < NSLOT; ++sl) {
            r1 += part[(size_t)sl * (2 * N) + i];
            r2 += part[(size_t)sl * (2 * N) + N + i];
        }
        s += 0.5f * (logf(r1 - E5) + logf(r2 - E5)) - d12[i];
    }
    sm[threadIdx.x] = s;
    __syncthreads();
    for (int w = 128; w > 0; w >>= 1) {
        if (threadIdx.x < w) sm[threadIdx.x] += sm[threadIdx.x + w];
        __syncthreads();
    }
    if (threadIdx.x == 0) atomicAdd(out, sm[0] / (float)N);
}

extern "C" void kernel_launch(void* const* d_in, const int* in_sizes, int n_in,
                              void* d_out, int out_size, void* d_ws, size_t ws_size,
                              hipStream_t stream) {
    const float* h1 = (const float*)d_in[0];
    const float* h2 = (const float*)d_in[1];
    const int N = in_sizes[0] / D;   // 8192

    unsigned char* P = (unsigned char*)d_ws;                // 2N x 128 fp8, frag-major
    float* part = (float*)(P + (size_t)2 * N * D);          // 145 x 2N partials
    float* d12  = part + (size_t)NSLOT * 2 * N;             // N
    float* out  = (float*)d_out;

    normalize_kernel<<<N / 32, 256, 0, stream>>>(
        (const float4*)h1, (const float4*)h2, P, d12, out, N);

    dim3 grid(128, 17, 2);
    gram_mfma_kernel<<<grid, 256, 0, stream>>>(P, part, N);

    loss_reduce_kernel<<<64, 256, 0, stream>>>(part, d12, out, N);
}